// Round 6
// baseline (35.035 us; speedup 1.0000x reference)
//
#include <hip/hip_runtime.h>
#include <math.h>

#define IMG  1024
#define ROWS 8      // output rows per block -> 128 x 16 = 2048 blocks

#define NEG4 make_float4(-INFINITY, -INFINITY, -INFINITY, -INFINITY)

typedef float f32x4 __attribute__((ext_vector_type(4)));

__device__ __forceinline__ float4 max4(const float4 a, const float4 b) {
    return make_float4(fmaxf(a.x, b.x), fmaxf(a.y, b.y),
                       fmaxf(a.z, b.z), fmaxf(a.w, b.w));
}

// sliding 9-wide max: 4 outputs from 12 inputs (v0=a0..3, v1=a4..7, v2=a8..11)
__device__ __forceinline__ float4 hmax9(const float4 v0, const float4 v1, const float4 v2) {
    const float core = fmaxf(fmaxf(fmaxf(v0.w, v1.x), fmaxf(v1.y, v1.z)),
                             fmaxf(v1.w, v2.x));                     // a3..a8
    const float p12  = fmaxf(v0.y, v0.z);
    const float q910 = fmaxf(v2.y, v2.z);
    float4 r;
    r.x = fmaxf(core, fmaxf(v0.x, p12));        // a0..a8
    r.y = fmaxf(core, fmaxf(p12, v2.y));        // a1..a9
    r.z = fmaxf(core, fmaxf(v0.z, q910));       // a2..a10
    r.w = fmaxf(core, fmaxf(q910, v2.w));       // a3..a11
    return r;
}

__device__ __forceinline__ void store_nt(float* addr, const float4 v) {
    f32x4 t;
    t.x = v.x; t.y = v.y; t.z = v.z; t.w = v.w;
    __builtin_nontemporal_store(t, reinterpret_cast<f32x4*>(addr));
}

__global__ __launch_bounds__(256) void dilate9x9(const float* __restrict__ in,
                                                 float* __restrict__ out) {
    const int x0 = threadIdx.x << 2;          // thread's 4 output columns
    const int y0 = blockIdx.x * ROWS;
    const int b  = blockIdx.y;

    const float* img  = in  + (size_t)b * IMG * IMG;
    float*       oimg = out + (size_t)b * IMG * IMG;

    const bool hasL = (x0 >= 4);
    const bool hasR = (x0 <= IMG - 8);

    float4 C[8];   // carried hmax rows: rows y0-4 .. y0+3

    // ---- prologue: rows y0-4 .. y0+3 (24 clustered loads) ------------------
    {
        float4 L0[8], L1[8], L2[8];
        bool   val[8];
        #pragma unroll
        for (int j = 0; j < 8; ++j) {
            const int iy = y0 - 4 + j;
            val[j] = (iy >= 0);               // iy < IMG always (y0+3 <= 1019)
            const int cy = val[j] ? iy : 0;
            const float4* p = reinterpret_cast<const float4*>(img + (size_t)cy * IMG + x0);
            L1[j] = p[0];
            L0[j] = *(hasL ? p - 1 : p);      // address-select keeps load unconditional
            L2[j] = *(hasR ? p + 1 : p);
        }
        #pragma unroll
        for (int j = 0; j < 8; ++j) {
            const float4 l0 = hasL ? L0[j] : NEG4;
            const float4 l2 = hasR ? L2[j] : NEG4;
            C[j] = val[j] ? hmax9(l0, L1[j], l2) : NEG4;
        }
    }

    // ---- single chunk of 8 output rows -------------------------------------
    {
        const int r0 = y0;

        float4 L0[8], L1[8], L2[8];
        bool   val[8];
        #pragma unroll
        for (int j = 0; j < 8; ++j) {         // 24 loads for rows r0+4 .. r0+11
            const int iy = r0 + 4 + j;
            val[j] = (iy < IMG);              // iy >= 0 always
            const int cy = val[j] ? iy : IMG - 1;
            const float4* p = reinterpret_cast<const float4*>(img + (size_t)cy * IMG + x0);
            L1[j] = p[0];
            L0[j] = *(hasL ? p - 1 : p);
            L2[j] = *(hasR ? p + 1 : p);
        }

        // suffix max over carry (independent of the loads above)
        float4 S[8];
        S[7] = C[7];
        #pragma unroll
        for (int j = 6; j >= 0; --j) S[j] = max4(C[j], S[j + 1]);

        // consume: running prefix + nontemporal store (don't pollute L2/L3)
        float4 P;
        #pragma unroll
        for (int t = 0; t < 8; ++t) {
            const float4 l0 = hasL ? L0[t] : NEG4;
            const float4 l2 = hasR ? L2[t] : NEG4;
            const float4 H  = val[t] ? hmax9(l0, L1[t], l2) : NEG4;
            P = (t == 0) ? H : max4(P, H);
            const float4 o = max4(S[t], P);
            store_nt(oimg + (size_t)(r0 + t) * IMG + x0, o);
        }
    }
}

extern "C" void kernel_launch(void* const* d_in, const int* in_sizes, int n_in,
                              void* d_out, int out_size, void* d_ws, size_t ws_size,
                              hipStream_t stream) {
    const float* in  = (const float*)d_in[0];
    float*       out = (float*)d_out;
    const int B = in_sizes[0] / (IMG * IMG);   // 16
    dim3 grid(IMG / ROWS, B);                  // 128 x 16 = 2048 blocks
    dilate9x9<<<grid, 256, 0, stream>>>(in, out);
}

// Round 7
// 30.681 us; speedup vs baseline: 1.1419x; 1.1419x over previous
//
#include <hip/hip_runtime.h>
#include <math.h>

#define IMG  1024
#define ROWS 16     // 64 x 16 = 1024 blocks

#define NEG4 make_float4(-INFINITY, -INFINITY, -INFINITY, -INFINITY)

__device__ __forceinline__ float4 max4(const float4 a, const float4 b) {
    return make_float4(fmaxf(a.x, b.x), fmaxf(a.y, b.y),
                       fmaxf(a.z, b.z), fmaxf(a.w, b.w));
}

__global__ __launch_bounds__(256, 2)
void dilate9x9(const float* __restrict__ in, float* __restrict__ out) {
    const int tid  = threadIdx.x;
    const int lane = tid & 63;
    const int x0   = tid << 2;                // thread's 4 columns (block spans full row)
    const int y0   = blockIdx.x * ROWS;
    const int b    = blockIdx.y;

    const float* img  = in  + (size_t)b * IMG * IMG;
    float*       oimg = out + (size_t)b * IMG * IMG;

    // wave-edge lanes fetch the adjacent float4 (cross-wave neighbor) themselves
    const bool eL = (lane == 0)  && (x0 > 0);
    const bool eR = (lane == 63) && (x0 < IMG - 4);
    const int  xe = eL ? (x0 - 4) : (x0 + 4);

    // horizontal sliding max-9 for one row from ONE aligned load per lane.
    // v = own float4; e = edge float4 (only lanes 0/63; NEG4 at image border).
    auto hmax_row = [&](const float4 v, const float4 e) -> float4 {
        const float pre1 = fmaxf(v.x, v.y);
        const float pre2 = fmaxf(pre1, v.z);
        const float pre3 = fmaxf(pre2, v.w);
        const float suf2 = fmaxf(v.z, v.w);
        const float suf1 = fmaxf(v.y, suf2);
        const float suf0 = fmaxf(v.x, suf1);   // = max of my 4 floats
        // prev lane's suffixes, next lane's prefixes
        float ps0 = __shfl_up(suf0, 1, 64);
        float ps1 = __shfl_up(suf1, 1, 64);
        float ps2 = __shfl_up(suf2, 1, 64);
        float ps3 = __shfl_up(v.w , 1, 64);
        float np0 = __shfl_down(v.x , 1, 64);
        float np1 = __shfl_down(pre1, 1, 64);
        float np2 = __shfl_down(pre2, 1, 64);
        float np3 = __shfl_down(pre3, 1, 64);
        if (lane == 0) {                       // patch from edge load (left)
            ps3 = e.w;
            ps2 = fmaxf(e.z, e.w);
            ps1 = fmaxf(e.y, ps2);
            ps0 = fmaxf(e.x, ps1);
        }
        if (lane == 63) {                      // patch from edge load (right)
            np0 = e.x;
            np1 = fmaxf(e.x, e.y);
            np2 = fmaxf(np1, e.z);
            np3 = fmaxf(np2, e.w);
        }
        float4 r;                              // out[j] = max(prev.suf[j], mineAll, next.pre[j])
        r.x = fmaxf(fmaxf(ps0, suf0), np0);
        r.y = fmaxf(fmaxf(ps1, suf0), np1);
        r.z = fmaxf(fmaxf(ps2, suf0), np2);
        r.w = fmaxf(fmaxf(ps3, suf0), np3);
        return r;
    };

    float4 C[8];   // carried hmax rows y0-4 .. y0+3

    // ---- prologue: 8 clustered row loads, then compute ----------------------
    {
        float4 V[8], E[8];
        bool   val[8];
        #pragma unroll
        for (int j = 0; j < 8; ++j) {
            const int iy = y0 - 4 + j;         // block-uniform
            val[j] = (iy >= 0);
            const size_t ro = (size_t)(val[j] ? iy : 0) * IMG;
            V[j] = *reinterpret_cast<const float4*>(img + ro + x0);
            E[j] = NEG4;
            if (eL | eR) E[j] = *reinterpret_cast<const float4*>(img + ro + xe);
        }
        #pragma unroll
        for (int j = 0; j < 8; ++j)
            C[j] = val[j] ? hmax_row(V[j], E[j]) : NEG4;
    }

    // ---- 2 chunks of 8 output rows ------------------------------------------
    #pragma unroll
    for (int c = 0; c < ROWS / 8; ++c) {
        const int r0 = y0 + (c << 3);

        float4 V[8], E[8];
        bool   val[8];
        #pragma unroll
        for (int j = 0; j < 8; ++j) {          // clustered loads rows r0+4 .. r0+11
            const int iy = r0 + 4 + j;         // block-uniform
            val[j] = (iy < IMG);
            const size_t ro = (size_t)(val[j] ? iy : IMG - 1) * IMG;
            V[j] = *reinterpret_cast<const float4*>(img + ro + x0);
            E[j] = NEG4;
            if (eL | eR) E[j] = *reinterpret_cast<const float4*>(img + ro + xe);
        }

        // suffix max over carry (independent of the loads above)
        float4 S[8];
        S[7] = C[7];
        #pragma unroll
        for (int j = 6; j >= 0; --j) S[j] = max4(C[j], S[j + 1]);

        // consume: hmax per new row, running prefix, store
        float4 P;
        #pragma unroll
        for (int t = 0; t < 8; ++t) {
            const float4 H = val[t] ? hmax_row(V[t], E[t]) : NEG4;
            P = (t == 0) ? H : max4(P, H);
            *reinterpret_cast<float4*>(oimg + (size_t)(r0 + t) * IMG + x0) = max4(S[t], P);
            C[t] = H;
        }
    }
}

extern "C" void kernel_launch(void* const* d_in, const int* in_sizes, int n_in,
                              void* d_out, int out_size, void* d_ws, size_t ws_size,
                              hipStream_t stream) {
    const float* in  = (const float*)d_in[0];
    float*       out = (float*)d_out;
    const int B = in_sizes[0] / (IMG * IMG);   // 16
    dim3 grid(IMG / ROWS, B);                  // 64 x 16 = 1024 blocks
    dilate9x9<<<grid, 256, 0, stream>>>(in, out);
}

// Round 8
// 29.098 us; speedup vs baseline: 1.2040x; 1.0544x over previous
//
#include <hip/hip_runtime.h>
#include <math.h>

#define IMG  1024
#define ROWS 32     // 32 x 16 = 512 blocks -> 2 resident blocks/CU, no dispatch churn

#define NEG4 make_float4(-INFINITY, -INFINITY, -INFINITY, -INFINITY)

__device__ __forceinline__ float4 max4(const float4 a, const float4 b) {
    return make_float4(fmaxf(a.x, b.x), fmaxf(a.y, b.y),
                       fmaxf(a.z, b.z), fmaxf(a.w, b.w));
}

__global__ __launch_bounds__(256, 1)
void dilate9x9(const float* __restrict__ in, float* __restrict__ out) {
    const int tid  = threadIdx.x;
    const int lane = tid & 63;
    const int x0   = tid << 2;                // thread's 4 columns (block spans full row)
    const int y0   = blockIdx.x * ROWS;
    const int b    = blockIdx.y;

    const float* img  = in  + (size_t)b * IMG * IMG;
    float*       oimg = out + (size_t)b * IMG * IMG;

    // wave-edge lanes fetch the adjacent float4 (cross-wave neighbor) themselves
    const bool eL = (lane == 0)  && (x0 > 0);
    const bool eR = (lane == 63) && (x0 < IMG - 4);
    const int  xe = eL ? (x0 - 4) : (x0 + 4);

    // horizontal sliding max-9 for one row from ONE aligned load per lane.
    // v = own float4; e = edge float4 (only lanes 0/63; NEG4 at image border).
    auto hmax_row = [&](const float4 v, const float4 e) -> float4 {
        const float pre1 = fmaxf(v.x, v.y);
        const float pre2 = fmaxf(pre1, v.z);
        const float pre3 = fmaxf(pre2, v.w);
        const float suf2 = fmaxf(v.z, v.w);
        const float suf1 = fmaxf(v.y, suf2);
        const float suf0 = fmaxf(v.x, suf1);   // = max of my 4 floats
        // prev lane's suffixes, next lane's prefixes
        float ps0 = __shfl_up(suf0, 1, 64);
        float ps1 = __shfl_up(suf1, 1, 64);
        float ps2 = __shfl_up(suf2, 1, 64);
        float ps3 = __shfl_up(v.w , 1, 64);
        float np0 = __shfl_down(v.x , 1, 64);
        float np1 = __shfl_down(pre1, 1, 64);
        float np2 = __shfl_down(pre2, 1, 64);
        float np3 = __shfl_down(pre3, 1, 64);
        if (lane == 0) {                       // patch from edge load (left)
            ps3 = e.w;
            ps2 = fmaxf(e.z, e.w);
            ps1 = fmaxf(e.y, ps2);
            ps0 = fmaxf(e.x, ps1);
        }
        if (lane == 63) {                      // patch from edge load (right)
            np0 = e.x;
            np1 = fmaxf(e.x, e.y);
            np2 = fmaxf(np1, e.z);
            np3 = fmaxf(np2, e.w);
        }
        float4 r;                              // out[j] = max(prev.suf[j], mineAll, next.pre[j])
        r.x = fmaxf(fmaxf(ps0, suf0), np0);
        r.y = fmaxf(fmaxf(ps1, suf0), np1);
        r.z = fmaxf(fmaxf(ps2, suf0), np2);
        r.w = fmaxf(fmaxf(ps3, suf0), np3);
        return r;
    };

    float4 C[8];   // carried hmax rows y0-4 .. y0+3

    // ---- prologue: 8 clustered row loads, then compute ----------------------
    {
        float4 V[8], E[8];
        bool   val[8];
        #pragma unroll
        for (int j = 0; j < 8; ++j) {
            const int iy = y0 - 4 + j;         // block-uniform
            val[j] = (iy >= 0);
            const size_t ro = (size_t)(val[j] ? iy : 0) * IMG;
            V[j] = *reinterpret_cast<const float4*>(img + ro + x0);
            E[j] = NEG4;
            if (eL | eR) E[j] = *reinterpret_cast<const float4*>(img + ro + xe);
        }
        #pragma unroll
        for (int j = 0; j < 8; ++j)
            C[j] = val[j] ? hmax_row(V[j], E[j]) : NEG4;
    }

    // ---- 4 chunks of 8 output rows ------------------------------------------
    #pragma unroll
    for (int c = 0; c < ROWS / 8; ++c) {
        const int r0 = y0 + (c << 3);

        float4 V[8], E[8];
        bool   val[8];
        #pragma unroll
        for (int j = 0; j < 8; ++j) {          // clustered loads rows r0+4 .. r0+11
            const int iy = r0 + 4 + j;         // block-uniform
            val[j] = (iy < IMG);
            const size_t ro = (size_t)(val[j] ? iy : IMG - 1) * IMG;
            V[j] = *reinterpret_cast<const float4*>(img + ro + x0);
            E[j] = NEG4;
            if (eL | eR) E[j] = *reinterpret_cast<const float4*>(img + ro + xe);
        }

        // suffix max over carry (independent of the loads above)
        float4 S[8];
        S[7] = C[7];
        #pragma unroll
        for (int j = 6; j >= 0; --j) S[j] = max4(C[j], S[j + 1]);

        // consume: hmax per new row, running prefix, store
        float4 P;
        #pragma unroll
        for (int t = 0; t < 8; ++t) {
            const float4 H = val[t] ? hmax_row(V[t], E[t]) : NEG4;
            P = (t == 0) ? H : max4(P, H);
            *reinterpret_cast<float4*>(oimg + (size_t)(r0 + t) * IMG + x0) = max4(S[t], P);
            C[t] = H;
        }
    }
}

extern "C" void kernel_launch(void* const* d_in, const int* in_sizes, int n_in,
                              void* d_out, int out_size, void* d_ws, size_t ws_size,
                              hipStream_t stream) {
    const float* in  = (const float*)d_in[0];
    float*       out = (float*)d_out;
    const int B = in_sizes[0] / (IMG * IMG);   // 16
    dim3 grid(IMG / ROWS, B);                  // 32 x 16 = 512 blocks
    dilate9x9<<<grid, 256, 0, stream>>>(in, out);
}

// Round 9
// 28.974 us; speedup vs baseline: 1.2092x; 1.0043x over previous
//
#include <hip/hip_runtime.h>
#include <math.h>

#define IMG  1024
#define ROWS 32     // 32 x 16 = 512 blocks -> 2 resident blocks/CU

#define NEG4 make_float4(-INFINITY, -INFINITY, -INFINITY, -INFINITY)

__device__ __forceinline__ float4 max4(const float4 a, const float4 b) {
    return make_float4(fmaxf(a.x, b.x), fmaxf(a.y, b.y),
                       fmaxf(a.z, b.z), fmaxf(a.w, b.w));
}

__global__ __launch_bounds__(256, 1)
void dilate9x9(const float* __restrict__ in, float* __restrict__ out) {
    const int tid  = threadIdx.x;
    const int lane = tid & 63;
    const int x0   = tid << 2;                // thread's 4 columns (block spans full row)
    const int y0   = blockIdx.x * ROWS;
    const int b    = blockIdx.y;

    const float* img  = in  + (size_t)b * IMG * IMG;
    float*       oimg = out + (size_t)b * IMG * IMG;

    // wave-edge lanes fetch the adjacent float4 (cross-wave neighbor) themselves
    const bool eL = (lane == 0)  && (x0 > 0);
    const bool eR = (lane == 63) && (x0 < IMG - 4);
    const int  xe = eL ? (x0 - 4) : (x0 + 4);

    // horizontal sliding max-9 for one row from ONE aligned load per lane.
    auto hmax_row = [&](const float4 v, const float4 e) -> float4 {
        const float pre1 = fmaxf(v.x, v.y);
        const float pre2 = fmaxf(pre1, v.z);
        const float pre3 = fmaxf(pre2, v.w);
        const float suf2 = fmaxf(v.z, v.w);
        const float suf1 = fmaxf(v.y, suf2);
        const float suf0 = fmaxf(v.x, suf1);   // = max of my 4 floats
        float ps0 = __shfl_up(suf0, 1, 64);
        float ps1 = __shfl_up(suf1, 1, 64);
        float ps2 = __shfl_up(suf2, 1, 64);
        float ps3 = __shfl_up(v.w , 1, 64);
        float np0 = __shfl_down(v.x , 1, 64);
        float np1 = __shfl_down(pre1, 1, 64);
        float np2 = __shfl_down(pre2, 1, 64);
        float np3 = __shfl_down(pre3, 1, 64);
        if (lane == 0) {                       // patch from edge load (left)
            ps3 = e.w;
            ps2 = fmaxf(e.z, e.w);
            ps1 = fmaxf(e.y, ps2);
            ps0 = fmaxf(e.x, ps1);
        }
        if (lane == 63) {                      // patch from edge load (right)
            np0 = e.x;
            np1 = fmaxf(e.x, e.y);
            np2 = fmaxf(np1, e.z);
            np3 = fmaxf(np2, e.w);
        }
        float4 r;
        r.x = fmaxf(fmaxf(ps0, suf0), np0);
        r.y = fmaxf(fmaxf(ps1, suf0), np1);
        r.z = fmaxf(fmaxf(ps2, suf0), np2);
        r.w = fmaxf(fmaxf(ps3, suf0), np3);
        return r;
    };

    // 8 clustered row loads starting at iyBase (block-uniform); clamp low or high
    auto load8 = [&](float4 (&V)[8], float4 (&E)[8], const int iyBase, const bool clampHi) {
        #pragma unroll
        for (int j = 0; j < 8; ++j) {
            const int iy = iyBase + j;
            const int cy = clampHi ? (iy < IMG ? iy : IMG - 1) : (iy >= 0 ? iy : 0);
            const size_t ro = (size_t)cy * IMG;
            V[j] = *reinterpret_cast<const float4*>(img + ro + x0);
            E[j] = NEG4;
            if (eL | eR) E[j] = *reinterpret_cast<const float4*>(img + ro + xe);
        }
    };

    float4 C[8];                 // carried hmax rows
    float4 V0[8], E0[8], V1[8], E1[8];

    // ---- prologue: rows y0-4 .. y0+3 into buf0, compute C -------------------
    load8(V0, E0, y0 - 4, false);
    #pragma unroll
    for (int j = 0; j < 8; ++j)
        C[j] = (y0 - 4 + j >= 0) ? hmax_row(V0[j], E0[j]) : NEG4;

    // ---- chunk 0's input rows y0+4 .. y0+11 into buf0 (reuse) ---------------
    load8(V0, E0, y0 + 4, true);

    // one chunk: prefetch next rows into (Vn,En), consume (Vc,Ec)
    auto chunk = [&](const int c, float4 (&Vc)[8], float4 (&Ec)[8],
                     float4 (&Vn)[8], float4 (&En)[8]) {
        const int r0 = y0 + (c << 3);
        if (c < (ROWS / 8) - 1) load8(Vn, En, r0 + 12, true);   // prefetch chunk c+1

        float4 S[8];                                   // suffix scan over carry
        S[7] = C[7];
        #pragma unroll
        for (int j = 6; j >= 0; --j) S[j] = max4(C[j], S[j + 1]);

        float4 P;
        #pragma unroll
        for (int t = 0; t < 8; ++t) {
            const float4 H = (r0 + 4 + t < IMG) ? hmax_row(Vc[t], Ec[t]) : NEG4;
            P = (t == 0) ? H : max4(P, H);
            *reinterpret_cast<float4*>(oimg + (size_t)(r0 + t) * IMG + x0) = max4(S[t], P);
            C[t] = H;
        }
    };

    chunk(0, V0, E0, V1, E1);
    chunk(1, V1, E1, V0, E0);
    chunk(2, V0, E0, V1, E1);
    chunk(3, V1, E1, V0, E0);
}

extern "C" void kernel_launch(void* const* d_in, const int* in_sizes, int n_in,
                              void* d_out, int out_size, void* d_ws, size_t ws_size,
                              hipStream_t stream) {
    const float* in  = (const float*)d_in[0];
    float*       out = (float*)d_out;
    const int B = in_sizes[0] / (IMG * IMG);   // 16
    dim3 grid(IMG / ROWS, B);                  // 32 x 16 = 512 blocks
    dilate9x9<<<grid, 256, 0, stream>>>(in, out);
}

// Round 10
// 28.972 us; speedup vs baseline: 1.2093x; 1.0000x over previous
//
#include <hip/hip_runtime.h>
#include <math.h>

#define IMG  1024
#define ROWS 32     // 32 x 16 = 512 blocks -> 2 resident blocks/CU

#define NEG4 make_float4(-INFINITY, -INFINITY, -INFINITY, -INFINITY)

__device__ __forceinline__ float4 max4(const float4 a, const float4 b) {
    return make_float4(fmaxf(a.x, b.x), fmaxf(a.y, b.y),
                       fmaxf(a.z, b.z), fmaxf(a.w, b.w));
}

__global__ __launch_bounds__(256, 1)
void dilate9x9(const float* __restrict__ in, float* __restrict__ out) {
    const int tid  = threadIdx.x;
    const int lane = tid & 63;
    const int x0   = tid << 2;                // thread's 4 columns (block spans full row)
    const int y0   = blockIdx.x * ROWS;
    const int b    = blockIdx.y;

    const float* img  = in  + (size_t)b * IMG * IMG;
    float*       oimg = out + (size_t)b * IMG * IMG;

    // wave-edge lanes fetch the adjacent float4 (cross-wave neighbor) themselves
    const bool eL = (lane == 0)  && (x0 > 0);
    const bool eR = (lane == 63) && (x0 < IMG - 4);
    const int  xe = eL ? (x0 - 4) : (x0 + 4);

    // horizontal sliding max-9 for one row from ONE aligned load per lane.
    auto hmax_row = [&](const float4 v, const float4 e) -> float4 {
        const float pre1 = fmaxf(v.x, v.y);
        const float pre2 = fmaxf(pre1, v.z);
        const float pre3 = fmaxf(pre2, v.w);
        const float suf2 = fmaxf(v.z, v.w);
        const float suf1 = fmaxf(v.y, suf2);
        const float suf0 = fmaxf(v.x, suf1);   // = max of my 4 floats
        float ps0 = __shfl_up(suf0, 1, 64);
        float ps1 = __shfl_up(suf1, 1, 64);
        float ps2 = __shfl_up(suf2, 1, 64);
        float ps3 = __shfl_up(v.w , 1, 64);
        float np0 = __shfl_down(v.x , 1, 64);
        float np1 = __shfl_down(pre1, 1, 64);
        float np2 = __shfl_down(pre2, 1, 64);
        float np3 = __shfl_down(pre3, 1, 64);
        if (lane == 0) {                       // patch from edge load (left)
            ps3 = e.w;
            ps2 = fmaxf(e.z, e.w);
            ps1 = fmaxf(e.y, ps2);
            ps0 = fmaxf(e.x, ps1);
        }
        if (lane == 63) {                      // patch from edge load (right)
            np0 = e.x;
            np1 = fmaxf(e.x, e.y);
            np2 = fmaxf(np1, e.z);
            np3 = fmaxf(np2, e.w);
        }
        float4 r;
        r.x = fmaxf(fmaxf(ps0, suf0), np0);
        r.y = fmaxf(fmaxf(ps1, suf0), np1);
        r.z = fmaxf(fmaxf(ps2, suf0), np2);
        r.w = fmaxf(fmaxf(ps3, suf0), np3);
        return r;
    };

    // 8 clustered row loads starting at iyBase (block-uniform); clamp low or high.
    // V-loads issue as one unbroken cluster; divergent edge loads in ONE branch.
    auto load8 = [&](float4 (&V)[8], float4 (&E)[8], const int iyBase, const bool clampHi) {
        size_t ro[8];
        #pragma unroll
        for (int j = 0; j < 8; ++j) {
            const int iy = iyBase + j;
            const int cy = clampHi ? (iy < IMG ? iy : IMG - 1) : (iy >= 0 ? iy : 0);
            ro[j] = (size_t)cy * IMG;
            V[j] = *reinterpret_cast<const float4*>(img + ro[j] + x0);
        }
        #pragma unroll
        for (int j = 0; j < 8; ++j) E[j] = NEG4;
        if (eL | eR) {
            #pragma unroll
            for (int j = 0; j < 8; ++j)
                E[j] = *reinterpret_cast<const float4*>(img + ro[j] + xe);
        }
    };

    float4 C[8];                 // carried hmax rows
    float4 V0[8], E0[8], V1[8], E1[8];

    // ---- prologue: rows y0-4 .. y0+3 into buf0, compute C -------------------
    load8(V0, E0, y0 - 4, false);
    #pragma unroll
    for (int j = 0; j < 8; ++j)
        C[j] = (y0 - 4 + j >= 0) ? hmax_row(V0[j], E0[j]) : NEG4;

    // ---- chunk 0's input rows y0+4 .. y0+11 into buf0 (reuse) ---------------
    load8(V0, E0, y0 + 4, true);
    __builtin_amdgcn_sched_barrier(0);         // pin: loads stay issued here

    // one chunk: prefetch next rows into (Vn,En), consume (Vc,Ec)
    auto chunk = [&](const int c, float4 (&Vc)[8], float4 (&Ec)[8],
                     float4 (&Vn)[8], float4 (&En)[8]) {
        const int r0 = y0 + (c << 3);
        if (c < (ROWS / 8) - 1) {
            load8(Vn, En, r0 + 12, true);      // prefetch chunk c+1
            __builtin_amdgcn_sched_barrier(0); // do NOT sink these into consume
        }

        float4 S[8];                                   // suffix scan over carry
        S[7] = C[7];
        #pragma unroll
        for (int j = 6; j >= 0; --j) S[j] = max4(C[j], S[j + 1]);

        float4 P;
        #pragma unroll
        for (int t = 0; t < 8; ++t) {
            const float4 H = (r0 + 4 + t < IMG) ? hmax_row(Vc[t], Ec[t]) : NEG4;
            P = (t == 0) ? H : max4(P, H);
            *reinterpret_cast<float4*>(oimg + (size_t)(r0 + t) * IMG + x0) = max4(S[t], P);
            C[t] = H;
        }
    };

    chunk(0, V0, E0, V1, E1);
    chunk(1, V1, E1, V0, E0);
    chunk(2, V0, E0, V1, E1);
    chunk(3, V1, E1, V0, E0);
}

extern "C" void kernel_launch(void* const* d_in, const int* in_sizes, int n_in,
                              void* d_out, int out_size, void* d_ws, size_t ws_size,
                              hipStream_t stream) {
    const float* in  = (const float*)d_in[0];
    float*       out = (float*)d_out;
    const int B = in_sizes[0] / (IMG * IMG);   // 16
    dim3 grid(IMG / ROWS, B);                  // 32 x 16 = 512 blocks
    dilate9x9<<<grid, 256, 0, stream>>>(in, out);
}